// Round 2
// baseline (453.936 us; speedup 1.0000x reference)
//
#include <hip/hip_runtime.h>
#include <hip/hip_bf16.h>

// a_mean_op: out = where(deg>0, segment_mean(relu(h @ W.T + b)[src], dst), hr)
// R8: gather restructure. R7 counters: gather 66.5us, FETCH 179MB vs 32MB
// compulsory (5.6x re-read amp, random src thrashing the 4MB/XCD L2s), only
// 44% HBM BW (latency-bound: 8 edges / 2KB in flight per wave).
//  (a) gather v3: 16-lane group per edge, short8_ 16B loads -> 4 edges per
//      wave-load, 4-deep unroll = 16 edges / 4KB outstanding per wave; no
//      cross-lane combine (group holds the full 256B row).
//  (b) src-banding: build_kernel insertion-sorts each node's eidx segment by
//      src (capped at deg<=64; pure perf hint). Concurrent waves then sweep
//      hr in ascending-src order ~in lockstep -> live band partially
//      L2-resident instead of all 25.6MB per XCD.

#define FEAT 128
#define BM 64
#define NPB 512              // nodes per bucket  (dst >> 9); needs N < 2^17

using bf16 = __hip_bfloat16;
typedef __attribute__((ext_vector_type(8))) short short8_;   // 8 x bf16
typedef __attribute__((ext_vector_type(4))) short bhalf4;    // 4 x bf16
typedef __attribute__((ext_vector_type(4))) float floatx4;

__device__ __forceinline__ bhalf4 cvt4(float4 f) {
    bhalf4 s;
    s[0] = __bfloat16_as_short(__float2bfloat16(f.x));
    s[1] = __bfloat16_as_short(__float2bfloat16(f.y));
    s[2] = __bfloat16_as_short(__float2bfloat16(f.z));
    s[3] = __bfloat16_as_short(__float2bfloat16(f.w));
    return s;
}
__device__ __forceinline__ float b2f(short s) {
    return __bfloat162float(__short_as_bfloat16(s));
}

// ---------------------------------------------------------------------------
// K0: bucket histogram over dst (LDS-aggregated) + [W fp32->bf16, 4 blocks]
// ---------------------------------------------------------------------------
__launch_bounds__(256)
__global__ void bhist_wcvt_kernel(const int* __restrict__ dst, int* __restrict__ bcnt, int E,
                                  const float* __restrict__ W, bf16* __restrict__ Wb,
                                  int hb, int B) {
    __shared__ int cnt[256];
    int bid = blockIdx.x;
    int t = threadIdx.x;
    if (bid < hb) {
        cnt[t] = 0;
        __syncthreads();
        int base = bid * 8192;
        #pragma unroll
        for (int i = 0; i < 32; ++i) {
            int e = base + i * 256 + t;
            if (e < E) atomicAdd(&cnt[dst[e] >> 9], 1);
        }
        __syncthreads();
        if (t < B && cnt[t]) atomicAdd(&bcnt[t], cnt[t]);
    } else {
        // W: 128*128 = 4096 float4 over 4 blocks
        int base = ((bid - hb) * 256 + t) * 4;
        #pragma unroll
        for (int i = 0; i < 4; ++i) {
            int v = base + i;
            ((bhalf4*)Wb)[v] = cvt4(((const float4*)W)[v]);
        }
    }
}

// ---------------------------------------------------------------------------
// K1: GEMM hr = bf16(relu(h @ Wb^T + b)); h staged fp32->bf16 in-kernel.
// ---------------------------------------------------------------------------
__launch_bounds__(256)
__global__ void gemm_kernel(const float* __restrict__ h, const bf16* __restrict__ Wb,
                            const float* __restrict__ b, bf16* __restrict__ hr, int M) {
    __shared__ bf16 sA[BM][136];
    __shared__ bf16 sW[FEAT][136];

    const int tid  = threadIdx.x;
    const int row0 = blockIdx.x * BM;

    #pragma unroll
    for (int i = 0; i < 8; ++i) {
        int v = i * 256 + tid;
        int r = v >> 4;
        int c = (v & 15) * 8;
        *(short8_*)(&sW[r][c]) = *(const short8_*)(Wb + (size_t)r * FEAT + c);
    }
    #pragma unroll
    for (int i = 0; i < 8; ++i) {
        int v = i * 256 + tid;
        int r = v >> 5;                 // 32 float4 per row
        int c = (v & 31) * 4;
        int row = row0 + r;
        float4 f = make_float4(0.f, 0.f, 0.f, 0.f);
        if (row < M) f = *(const float4*)(h + (size_t)row * FEAT + c);
        float4* ff = &f;
        bhalf4 s;
        s[0] = __bfloat16_as_short(__float2bfloat16(ff->x));
        s[1] = __bfloat16_as_short(__float2bfloat16(ff->y));
        s[2] = __bfloat16_as_short(__float2bfloat16(ff->z));
        s[3] = __bfloat16_as_short(__float2bfloat16(ff->w));
        *(bhalf4*)(&sA[r][c]) = s;
    }
    __syncthreads();

    const int wave = tid >> 6;
    const int lane = tid & 63;
    const int m    = lane & 15;
    const int ko   = (lane >> 4) * 8;

    floatx4 acc[8];
    #pragma unroll
    for (int t = 0; t < 8; ++t) acc[t] = floatx4{0.f, 0.f, 0.f, 0.f};

    #pragma unroll
    for (int k0 = 0; k0 < FEAT; k0 += 32) {
        short8_ afrag = *(const short8_*)(&sA[wave * 16 + m][k0 + ko]);
        #pragma unroll
        for (int nt = 0; nt < 8; ++nt) {
            short8_ bfrag = *(const short8_*)(&sW[nt * 16 + m][k0 + ko]);
            acc[nt] = __builtin_amdgcn_mfma_f32_16x16x32_bf16(afrag, bfrag, acc[nt], 0, 0, 0);
        }
    }

    const int rbase = row0 + wave * 16 + (lane >> 4) * 4;
    #pragma unroll
    for (int nt = 0; nt < 8; ++nt) {
        int col = nt * 16 + m;
        float bias = b[col];
        #pragma unroll
        for (int r = 0; r < 4; ++r) {
            int row = rbase + r;
            if (row < M) {
                float v = fmaxf(acc[nt][r] + bias, 0.0f);
                hr[(size_t)row * FEAT + col] = __float2bfloat16(v);
            }
        }
    }
}

// ---------------------------------------------------------------------------
// K2: exclusive scan of bucket counts (B <= 256) -> bbase[B+1] and cursor[B]
// ---------------------------------------------------------------------------
__launch_bounds__(256)
__global__ void bscan_kernel(const int* __restrict__ bcnt, int* __restrict__ bbase,
                             int* __restrict__ cursor, int B, int E) {
    __shared__ int sd[256];
    int t = threadIdx.x;
    int v = (t < B) ? bcnt[t] : 0;
    sd[t] = v;
    __syncthreads();
    for (int off = 1; off < 256; off <<= 1) {
        int y = (t >= off) ? sd[t - off] : 0;
        __syncthreads();
        sd[t] += y;
        __syncthreads();
    }
    int excl = sd[t] - v;
    if (t < B) { bbase[t] = excl; cursor[t] = excl; }
    if (t == 0) bbase[B] = E;
}

// ---------------------------------------------------------------------------
// K3: bin edges into bucket-contiguous regions of binned[] (in d_out).
// packed = src | (local_dst << 17).  One global atomic per (block, bucket).
// ---------------------------------------------------------------------------
__launch_bounds__(256)
__global__ void bin_kernel(const int* __restrict__ src, const int* __restrict__ dst,
                           int* __restrict__ cursor, int* __restrict__ binned,
                           int E, int B) {
    __shared__ int cnt[256];
    __shared__ int resv[256];
    __shared__ int cur[256];
    int t = threadIdx.x;
    cnt[t] = 0; cur[t] = 0;
    __syncthreads();
    int base = blockIdx.x * 8192;
    #pragma unroll
    for (int i = 0; i < 32; ++i) {
        int e = base + i * 256 + t;
        if (e < E) atomicAdd(&cnt[dst[e] >> 9], 1);
    }
    __syncthreads();
    if (t < B && cnt[t]) resv[t] = atomicAdd(&cursor[t], cnt[t]);
    __syncthreads();
    #pragma unroll
    for (int i = 0; i < 32; ++i) {
        int e = base + i * 256 + t;
        if (e < E) {
            int d = dst[e];
            int bk = d >> 9;
            int r = atomicAdd(&cur[bk], 1);
            binned[resv[bk] + r] = src[e] | ((d & (NPB - 1)) << 17);
        }
    }
}

// ---------------------------------------------------------------------------
// K4: per-bucket CSR build + per-node src-sort (banding hint for gather).
// ---------------------------------------------------------------------------
__launch_bounds__(256)
__global__ void build_kernel(const int* __restrict__ binned, const int* __restrict__ bbase,
                             int* __restrict__ rowptr, int* __restrict__ eidx,
                             int N, int E) {
    __shared__ int sdeg[NPB];   // becomes exclusive offsets after scan
    __shared__ int scur[NPB];
    __shared__ int ssc[256];
    int t = threadIdx.x;
    int bk = blockIdx.x;
    sdeg[t] = 0; sdeg[t + 256] = 0;
    scur[t] = 0; scur[t + 256] = 0;
    __syncthreads();

    int base = bbase[bk];
    int cnt  = bbase[bk + 1] - base;

    // pass 1: local degree count
    for (int i = t; i < cnt; i += 256) {
        int p = binned[base + i];
        atomicAdd(&sdeg[(p >> 17) & (NPB - 1)], 1);
    }
    __syncthreads();

    // scan NPB=512 entries with 256 threads (2 per thread)
    int d0 = sdeg[2 * t];
    int d1 = sdeg[2 * t + 1];
    int s  = d0 + d1;
    ssc[t] = s;
    __syncthreads();
    for (int off = 1; off < 256; off <<= 1) {
        int y = (t >= off) ? ssc[t - off] : 0;
        __syncthreads();
        ssc[t] += y;
        __syncthreads();
    }
    int excl0 = ssc[t] - s;     // exclusive for element 2t

    int node0 = bk * NPB + 2 * t;
    if (node0 < N)     rowptr[node0]     = base + excl0;
    if (node0 + 1 < N) rowptr[node0 + 1] = base + excl0 + d0;
    if (bk == 0 && t == 0) rowptr[N] = E;

    sdeg[2 * t]     = excl0;
    sdeg[2 * t + 1] = excl0 + d0;
    __syncthreads();

    // pass 2: fill eidx (writes land inside this bucket's ~33KB L2 window)
    for (int i = t; i < cnt; i += 256) {
        int p = binned[base + i];
        int ld = (p >> 17) & (NPB - 1);
        int slot = atomicAdd(&scur[ld], 1);
        eidx[base + sdeg[ld] + slot] = p & 0x1FFFF;
    }
    __syncthreads();

    // pass 3: src-sort each node's segment (insertion sort, L2-resident
    // window). Pure perf hint: concurrent gather waves then sweep hr in
    // ascending-src order ~in lockstep -> temporal banding. Cap at 64 to
    // bound worst-case O(deg^2).
    for (int n = t; n < NPB; n += 256) {
        int c = scur[n];
        if (c < 2 || c > 64) continue;
        int s0 = base + sdeg[n];
        for (int i = 1; i < c; ++i) {
            int key = eidx[s0 + i];
            int j = i - 1;
            while (j >= 0 && eidx[s0 + j] > key) {
                eidx[s0 + j + 1] = eidx[s0 + j];
                --j;
            }
            eidx[s0 + j + 1] = key;
        }
    }
}

// ---------------------------------------------------------------------------
// K5: gather v3. 16-lane group per node; each lane owns 16B (short8_) of the
// 256B row -> one wave-load serves 4 edges; 4-deep unroll = 16 edges / 4KB
// outstanding per wave; no cross-lane combine needed.
// ---------------------------------------------------------------------------
__launch_bounds__(256)
__global__ void gather_kernel(const bf16* __restrict__ hr,
                              const int* __restrict__ rowptr,
                              const int* __restrict__ eidx,
                              float* __restrict__ out, int N) {
    int node = blockIdx.x * 16 + (threadIdx.x >> 4);
    if (node >= N) return;
    int l16 = threadIdx.x & 15;

    int beg = rowptr[node];
    int end = rowptr[node + 1];

    const short8_* hp8 = (const short8_*)hr;   // 16 short8_ per 128-feat row

    float a0[8], a1[8], a2[8], a3[8];
    #pragma unroll
    for (int j = 0; j < 8; ++j) { a0[j] = 0.f; a1[j] = 0.f; a2[j] = 0.f; a3[j] = 0.f; }

    int e = beg;
    for (; e + 3 < end; e += 4) {
        int s0 = eidx[e + 0];
        int s1 = eidx[e + 1];
        int s2 = eidx[e + 2];
        int s3 = eidx[e + 3];
        short8_ v0 = hp8[(size_t)s0 * 16 + l16];
        short8_ v1 = hp8[(size_t)s1 * 16 + l16];
        short8_ v2 = hp8[(size_t)s2 * 16 + l16];
        short8_ v3 = hp8[(size_t)s3 * 16 + l16];
        #pragma unroll
        for (int j = 0; j < 8; ++j) a0[j] += b2f(v0[j]);
        #pragma unroll
        for (int j = 0; j < 8; ++j) a1[j] += b2f(v1[j]);
        #pragma unroll
        for (int j = 0; j < 8; ++j) a2[j] += b2f(v2[j]);
        #pragma unroll
        for (int j = 0; j < 8; ++j) a3[j] += b2f(v3[j]);
    }
    for (; e < end; ++e) {
        int s0 = eidx[e];
        short8_ v0 = hp8[(size_t)s0 * 16 + l16];
        #pragma unroll
        for (int j = 0; j < 8; ++j) a0[j] += b2f(v0[j]);
    }

    #pragma unroll
    for (int j = 0; j < 8; ++j) a0[j] += a1[j] + a2[j] + a3[j];

    int d = end - beg;
    float r[8];
    if (d > 0) {
        float inv = 1.0f / (float)d;
        #pragma unroll
        for (int j = 0; j < 8; ++j) r[j] = a0[j] * inv;
    } else {
        short8_ v = hp8[(size_t)node * 16 + l16];
        #pragma unroll
        for (int j = 0; j < 8; ++j) r[j] = b2f(v[j]);
    }

    float* op = out + (size_t)node * FEAT + l16 * 8;
    float4 lo = make_float4(r[0], r[1], r[2], r[3]);
    float4 hi = make_float4(r[4], r[5], r[6], r[7]);
    *(float4*)(op)     = lo;
    *(float4*)(op + 4) = hi;
}

// ---------------------------------------------------------------------------
extern "C" void kernel_launch(void* const* d_in, const int* in_sizes, int n_in,
                              void* d_out, int out_size, void* d_ws, size_t ws_size,
                              hipStream_t stream) {
    const float* h   = (const float*)d_in[0];
    const int*   src = (const int*)d_in[2];
    const int*   dst = (const int*)d_in[3];
    const float* W   = (const float*)d_in[4];
    const float* b   = (const float*)d_in[5];
    float* out = (float*)d_out;

    const int N = in_sizes[0] / FEAT;
    const int E = in_sizes[2];
    const int B = (N + NPB - 1) / NPB;          // buckets (<= 256 for N <= 128K)

    // ws: hr bf16[N*128] | Wb bf16[128*128] | rowptr int[N+1]
    //   | eidx int[E] | bcnt int[256] | bbase int[257] | cursor int[256]
    char* ws = (char*)d_ws;
    size_t off = 0;
    bf16* hr     = (bf16*)(ws + off); off += (size_t)N * FEAT * 2;
    bf16* Wb     = (bf16*)(ws + off); off += (size_t)FEAT * FEAT * 2;
    int*  rowptr = (int*)(ws + off);  off += (size_t)(N + 1) * 4;
    int*  eidx   = (int*)(ws + off);  off += (size_t)E * 4;
    int*  bcnt   = (int*)(ws + off);  off += 256 * 4;
    int*  bbase  = (int*)(ws + off);  off += 257 * 4;
    int*  cursor = (int*)(ws + off);  off += 256 * 4;

    // binned edge staging lives in d_out (dead before gather overwrites out)
    int* binned = (int*)d_out;

    (void)hipMemsetAsync(bcnt, 0, 256 * 4, stream);

    const int hb = (E + 8191) / 8192;
    bhist_wcvt_kernel<<<dim3(hb + 4), dim3(256), 0, stream>>>(dst, bcnt, E, W, Wb, hb, B);

    const int gb = (N + BM - 1) / BM;
    gemm_kernel<<<dim3(gb), dim3(256), 0, stream>>>(h, Wb, b, hr, N);

    bscan_kernel<<<dim3(1), dim3(256), 0, stream>>>(bcnt, bbase, cursor, B, E);
    bin_kernel<<<dim3(hb), dim3(256), 0, stream>>>(src, dst, cursor, binned, E, B);
    build_kernel<<<dim3(B), dim3(256), 0, stream>>>(binned, bbase, rowptr, eidx, N, E);
    gather_kernel<<<dim3((N + 15) / 16), dim3(256), 0, stream>>>(hr, rowptr, eidx, out, N);
}

// Round 3
// 307.908 us; speedup vs baseline: 1.4743x; 1.4743x over previous
//
#include <hip/hip_runtime.h>
#include <hip/hip_bf16.h>

// a_mean_op: out = where(deg>0, segment_mean(relu(h @ W.T + b)[src], dst), hr)
// R9: R8's per-node insertion sort regressed build 186us (serial global-mem
// O(deg^2) chains, VALUBusy 3.3%). Replace with FREE banding: counting-sort
// key = ldst*16 + (src>>13) (8192 LDS counters instead of 512). Scatter then
// emits each node's segment grouped by src band (16 bands x ~1.6MB of hr),
// so concurrent gather waves sweep hr in ~lockstep band order -> live set
// ~2-3 bands vs 25.6MB. Gather v3 (16-lane groups, 16B loads) kept.

#define FEAT 128
#define BM 64
#define NPB 512              // nodes per bucket  (dst >> 9); needs N < 2^17
#define NBAND 16             // src bands (src >> 13); needs N <= 2^17

using bf16 = __hip_bfloat16;
typedef __attribute__((ext_vector_type(8))) short short8_;   // 8 x bf16
typedef __attribute__((ext_vector_type(4))) short bhalf4;    // 4 x bf16
typedef __attribute__((ext_vector_type(4))) float floatx4;

__device__ __forceinline__ bhalf4 cvt4(float4 f) {
    bhalf4 s;
    s[0] = __bfloat16_as_short(__float2bfloat16(f.x));
    s[1] = __bfloat16_as_short(__float2bfloat16(f.y));
    s[2] = __bfloat16_as_short(__float2bfloat16(f.z));
    s[3] = __bfloat16_as_short(__float2bfloat16(f.w));
    return s;
}
__device__ __forceinline__ float b2f(short s) {
    return __bfloat162float(__short_as_bfloat16(s));
}

// ---------------------------------------------------------------------------
// K0: bucket histogram over dst (LDS-aggregated) + [W fp32->bf16, 4 blocks]
// ---------------------------------------------------------------------------
__launch_bounds__(256)
__global__ void bhist_wcvt_kernel(const int* __restrict__ dst, int* __restrict__ bcnt, int E,
                                  const float* __restrict__ W, bf16* __restrict__ Wb,
                                  int hb, int B) {
    __shared__ int cnt[256];
    int bid = blockIdx.x;
    int t = threadIdx.x;
    if (bid < hb) {
        cnt[t] = 0;
        __syncthreads();
        int base = bid * 8192;
        #pragma unroll
        for (int i = 0; i < 32; ++i) {
            int e = base + i * 256 + t;
            if (e < E) atomicAdd(&cnt[dst[e] >> 9], 1);
        }
        __syncthreads();
        if (t < B && cnt[t]) atomicAdd(&bcnt[t], cnt[t]);
    } else {
        // W: 4096 float4 over 4 blocks
        int base = ((bid - hb) * 256 + t) * 4;
        #pragma unroll
        for (int i = 0; i < 4; ++i) {
            int v = base + i;
            ((bhalf4*)Wb)[v] = cvt4(((const float4*)W)[v]);
        }
    }
}

// ---------------------------------------------------------------------------
// K1: GEMM hr = bf16(relu(h @ Wb^T + b)); h staged fp32->bf16 in-kernel.
// ---------------------------------------------------------------------------
__launch_bounds__(256)
__global__ void gemm_kernel(const float* __restrict__ h, const bf16* __restrict__ Wb,
                            const float* __restrict__ b, bf16* __restrict__ hr, int M) {
    __shared__ bf16 sA[BM][136];
    __shared__ bf16 sW[FEAT][136];

    const int tid  = threadIdx.x;
    const int row0 = blockIdx.x * BM;

    #pragma unroll
    for (int i = 0; i < 8; ++i) {
        int v = i * 256 + tid;
        int r = v >> 4;
        int c = (v & 15) * 8;
        *(short8_*)(&sW[r][c]) = *(const short8_*)(Wb + (size_t)r * FEAT + c);
    }
    #pragma unroll
    for (int i = 0; i < 8; ++i) {
        int v = i * 256 + tid;
        int r = v >> 5;                 // 32 float4 per row
        int c = (v & 31) * 4;
        int row = row0 + r;
        float4 f = make_float4(0.f, 0.f, 0.f, 0.f);
        if (row < M) f = *(const float4*)(h + (size_t)row * FEAT + c);
        *(bhalf4*)(&sA[r][c]) = cvt4(f);
    }
    __syncthreads();

    const int wave = tid >> 6;
    const int lane = tid & 63;
    const int m    = lane & 15;
    const int ko   = (lane >> 4) * 8;

    floatx4 acc[8];
    #pragma unroll
    for (int t = 0; t < 8; ++t) acc[t] = floatx4{0.f, 0.f, 0.f, 0.f};

    #pragma unroll
    for (int k0 = 0; k0 < FEAT; k0 += 32) {
        short8_ afrag = *(const short8_*)(&sA[wave * 16 + m][k0 + ko]);
        #pragma unroll
        for (int nt = 0; nt < 8; ++nt) {
            short8_ bfrag = *(const short8_*)(&sW[nt * 16 + m][k0 + ko]);
            acc[nt] = __builtin_amdgcn_mfma_f32_16x16x32_bf16(afrag, bfrag, acc[nt], 0, 0, 0);
        }
    }

    const int rbase = row0 + wave * 16 + (lane >> 4) * 4;
    #pragma unroll
    for (int nt = 0; nt < 8; ++nt) {
        int col = nt * 16 + m;
        float bias = b[col];
        #pragma unroll
        for (int r = 0; r < 4; ++r) {
            int row = rbase + r;
            if (row < M) {
                float v = fmaxf(acc[nt][r] + bias, 0.0f);
                hr[(size_t)row * FEAT + col] = __float2bfloat16(v);
            }
        }
    }
}

// ---------------------------------------------------------------------------
// K2: exclusive scan of bucket counts (B <= 256) -> bbase[B+1] and cursor[B]
// ---------------------------------------------------------------------------
__launch_bounds__(256)
__global__ void bscan_kernel(const int* __restrict__ bcnt, int* __restrict__ bbase,
                             int* __restrict__ cursor, int B, int E) {
    __shared__ int sd[256];
    int t = threadIdx.x;
    int v = (t < B) ? bcnt[t] : 0;
    sd[t] = v;
    __syncthreads();
    for (int off = 1; off < 256; off <<= 1) {
        int y = (t >= off) ? sd[t - off] : 0;
        __syncthreads();
        sd[t] += y;
        __syncthreads();
    }
    int excl = sd[t] - v;
    if (t < B) { bbase[t] = excl; cursor[t] = excl; }
    if (t == 0) bbase[B] = E;
}

// ---------------------------------------------------------------------------
// K3: bin edges into bucket-contiguous regions of binned[] (in d_out).
// packed = src | (local_dst << 17).  One global atomic per (block, bucket).
// ---------------------------------------------------------------------------
__launch_bounds__(256)
__global__ void bin_kernel(const int* __restrict__ src, const int* __restrict__ dst,
                           int* __restrict__ cursor, int* __restrict__ binned,
                           int E, int B) {
    __shared__ int cnt[256];
    __shared__ int resv[256];
    __shared__ int cur[256];
    int t = threadIdx.x;
    cnt[t] = 0; cur[t] = 0;
    __syncthreads();
    int base = blockIdx.x * 8192;
    #pragma unroll
    for (int i = 0; i < 32; ++i) {
        int e = base + i * 256 + t;
        if (e < E) atomicAdd(&cnt[dst[e] >> 9], 1);
    }
    __syncthreads();
    if (t < B && cnt[t]) resv[t] = atomicAdd(&cursor[t], cnt[t]);
    __syncthreads();
    #pragma unroll
    for (int i = 0; i < 32; ++i) {
        int e = base + i * 256 + t;
        if (e < E) {
            int d = dst[e];
            int bk = d >> 9;
            int r = atomicAdd(&cur[bk], 1);
            binned[resv[bk] + r] = src[e] | ((d & (NPB - 1)) << 17);
        }
    }
}

// ---------------------------------------------------------------------------
// K4: per-bucket CSR build, banded counting sort. key = ldst*16 + (src>>13).
// 8192 LDS counters; scan = 32-in-registers per thread + 256-wide block scan.
// rowptr read from band-0 counter post-scan; scatter consumes counters as
// cursors (atomicAdd). Edges land grouped by src band within each segment.
// ---------------------------------------------------------------------------
__launch_bounds__(256)
__global__ void build_kernel(const int* __restrict__ binned, const int* __restrict__ bbase,
                             int* __restrict__ rowptr, int* __restrict__ eidx,
                             int N, int E) {
    __shared__ int scnt[NPB * NBAND];   // 8192: exclusive offsets, then cursors
    __shared__ int ssc[256];
    int t = threadIdx.x;
    int bk = blockIdx.x;

    #pragma unroll
    for (int i = 0; i < NPB * NBAND / 256; ++i) scnt[i * 256 + t] = 0;
    __syncthreads();

    int base = bbase[bk];
    int cnt  = bbase[bk + 1] - base;

    // pass 1: banded histogram
    for (int i = t; i < cnt; i += 256) {
        int p  = binned[base + i];
        int sv = p & 0x1FFFF;
        int key = ((p >> 17) & (NPB - 1)) * NBAND + (sv >> 13);
        atomicAdd(&scnt[key], 1);
    }
    __syncthreads();

    // scan 8192 entries: thread t owns [t*32, t*32+32)
    int loc[32];
    int s = 0;
    #pragma unroll
    for (int i = 0; i < 32; ++i) { loc[i] = s; s += scnt[t * 32 + i]; }
    ssc[t] = s;
    __syncthreads();
    for (int off = 1; off < 256; off <<= 1) {
        int y = (t >= off) ? ssc[t - off] : 0;
        __syncthreads();
        ssc[t] += y;
        __syncthreads();
    }
    int ex = ssc[t] - s;
    #pragma unroll
    for (int i = 0; i < 32; ++i) scnt[t * 32 + i] = ex + loc[i];
    __syncthreads();

    // rowptr for this bucket's nodes (2 per thread), from band-0 counters
    int node0 = bk * NPB + 2 * t;
    if (node0 < N)     rowptr[node0]     = base + scnt[(2 * t) * NBAND];
    if (node0 + 1 < N) rowptr[node0 + 1] = base + scnt[(2 * t + 1) * NBAND];
    if (bk == 0 && t == 0) rowptr[N] = E;
    __syncthreads();

    // pass 2: scatter (destructive: scnt becomes per-key cursor)
    for (int i = t; i < cnt; i += 256) {
        int p  = binned[base + i];
        int sv = p & 0x1FFFF;
        int key = ((p >> 17) & (NPB - 1)) * NBAND + (sv >> 13);
        int pos = atomicAdd(&scnt[key], 1);
        eidx[base + pos] = sv;
    }
}

// ---------------------------------------------------------------------------
// K5: gather v3. 16-lane group per node; each lane owns 16B (short8_) of the
// 256B row -> one wave-load serves 4 edges; 4-deep unroll = 16 edges / 4KB
// outstanding per wave; no cross-lane combine needed.
// ---------------------------------------------------------------------------
__launch_bounds__(256)
__global__ void gather_kernel(const bf16* __restrict__ hr,
                              const int* __restrict__ rowptr,
                              const int* __restrict__ eidx,
                              float* __restrict__ out, int N) {
    int node = blockIdx.x * 16 + (threadIdx.x >> 4);
    if (node >= N) return;
    int l16 = threadIdx.x & 15;

    int beg = rowptr[node];
    int end = rowptr[node + 1];

    const short8_* hp8 = (const short8_*)hr;   // 16 short8_ per 128-feat row

    float a0[8], a1[8], a2[8], a3[8];
    #pragma unroll
    for (int j = 0; j < 8; ++j) { a0[j] = 0.f; a1[j] = 0.f; a2[j] = 0.f; a3[j] = 0.f; }

    int e = beg;
    for (; e + 3 < end; e += 4) {
        int s0 = eidx[e + 0];
        int s1 = eidx[e + 1];
        int s2 = eidx[e + 2];
        int s3 = eidx[e + 3];
        short8_ v0 = hp8[(size_t)s0 * 16 + l16];
        short8_ v1 = hp8[(size_t)s1 * 16 + l16];
        short8_ v2 = hp8[(size_t)s2 * 16 + l16];
        short8_ v3 = hp8[(size_t)s3 * 16 + l16];
        #pragma unroll
        for (int j = 0; j < 8; ++j) a0[j] += b2f(v0[j]);
        #pragma unroll
        for (int j = 0; j < 8; ++j) a1[j] += b2f(v1[j]);
        #pragma unroll
        for (int j = 0; j < 8; ++j) a2[j] += b2f(v2[j]);
        #pragma unroll
        for (int j = 0; j < 8; ++j) a3[j] += b2f(v3[j]);
    }
    for (; e < end; ++e) {
        int s0 = eidx[e];
        short8_ v0 = hp8[(size_t)s0 * 16 + l16];
        #pragma unroll
        for (int j = 0; j < 8; ++j) a0[j] += b2f(v0[j]);
    }

    #pragma unroll
    for (int j = 0; j < 8; ++j) a0[j] += a1[j] + a2[j] + a3[j];

    int d = end - beg;
    float r[8];
    if (d > 0) {
        float inv = 1.0f / (float)d;
        #pragma unroll
        for (int j = 0; j < 8; ++j) r[j] = a0[j] * inv;
    } else {
        short8_ v = hp8[(size_t)node * 16 + l16];
        #pragma unroll
        for (int j = 0; j < 8; ++j) r[j] = b2f(v[j]);
    }

    float* op = out + (size_t)node * FEAT + l16 * 8;
    *(float4*)(op)     = make_float4(r[0], r[1], r[2], r[3]);
    *(float4*)(op + 4) = make_float4(r[4], r[5], r[6], r[7]);
}

// ---------------------------------------------------------------------------
extern "C" void kernel_launch(void* const* d_in, const int* in_sizes, int n_in,
                              void* d_out, int out_size, void* d_ws, size_t ws_size,
                              hipStream_t stream) {
    const float* h   = (const float*)d_in[0];
    const int*   src = (const int*)d_in[2];
    const int*   dst = (const int*)d_in[3];
    const float* W   = (const float*)d_in[4];
    const float* b   = (const float*)d_in[5];
    float* out = (float*)d_out;

    const int N = in_sizes[0] / FEAT;
    const int E = in_sizes[2];
    const int B = (N + NPB - 1) / NPB;          // buckets (<= 256 for N <= 128K)

    // ws: hr bf16[N*128] | Wb bf16[128*128] | rowptr int[N+1]
    //   | eidx int[E] | bcnt int[256] | bbase int[257] | cursor int[256]
    char* ws = (char*)d_ws;
    size_t off = 0;
    bf16* hr     = (bf16*)(ws + off); off += (size_t)N * FEAT * 2;
    bf16* Wb     = (bf16*)(ws + off); off += (size_t)FEAT * FEAT * 2;
    int*  rowptr = (int*)(ws + off);  off += (size_t)(N + 1) * 4;
    int*  eidx   = (int*)(ws + off);  off += (size_t)E * 4;
    int*  bcnt   = (int*)(ws + off);  off += 256 * 4;
    int*  bbase  = (int*)(ws + off);  off += 257 * 4;
    int*  cursor = (int*)(ws + off);  off += 256 * 4;

    // binned edge staging lives in d_out (dead before gather overwrites out)
    int* binned = (int*)d_out;

    (void)hipMemsetAsync(bcnt, 0, 256 * 4, stream);

    const int hb = (E + 8191) / 8192;
    bhist_wcvt_kernel<<<dim3(hb + 4), dim3(256), 0, stream>>>(dst, bcnt, E, W, Wb, hb, B);

    const int gb = (N + BM - 1) / BM;
    gemm_kernel<<<dim3(gb), dim3(256), 0, stream>>>(h, Wb, b, hr, N);

    bscan_kernel<<<dim3(1), dim3(256), 0, stream>>>(bcnt, bbase, cursor, B, E);
    bin_kernel<<<dim3(hb), dim3(256), 0, stream>>>(src, dst, cursor, binned, E, B);
    build_kernel<<<dim3(B), dim3(256), 0, stream>>>(binned, bbase, rowptr, eidx, N, E);
    gather_kernel<<<dim3((N + 15) / 16), dim3(256), 0, stream>>>(hr, rowptr, eidx, out, N);
}